// Round 7
// baseline (318.968 us; speedup 1.0000x reference)
//
#include <hip/hip_runtime.h>
#include <math.h>

#define TT 2048
#define W 10

typedef short bf16x8 __attribute__((ext_vector_type(8)));
typedef float f32x4 __attribute__((ext_vector_type(4)));

#define MFMA16(a, b, c) __builtin_amdgcn_mfma_f32_16x16x32_bf16((a), (b), (c), 0, 0, 0)

// Truncation hi/lo bf16 split: lo absorbs hi's truncation error; residual ~2^-16.
__device__ __forceinline__ void splitTrunc(float v, unsigned short& hi,
                                           unsigned short& lo) {
  unsigned int u = __float_as_uint(v);
  hi = (unsigned short)(u >> 16);
  float r = v - __uint_as_float(u & 0xffff0000u);
  lo = (unsigned short)(__float_as_uint(r) >> 16);
}

// Register-array select by runtime index (cndmask chain — avoids scratch).
__device__ __forceinline__ float sel5(const float* d, int k) {
  float v = d[0];
  v = (k == 1) ? d[1] : v;
  v = (k == 2) ? d[2] : v;
  v = (k == 3) ? d[3] : v;
  v = (k == 4) ? d[4] : v;
  return v;
}

// ============== Kernel 1: row scan (ret, vol) + weight repack ==============
__global__ __launch_bounds__(256) void prep_kernel(
    const float* __restrict__ F, const float* __restrict__ p1,
    const float* __restrict__ p2, const float* __restrict__ p3,
    const float* __restrict__ p4, unsigned short* __restrict__ WtH,
    unsigned short* __restrict__ WtL, float* __restrict__ ret,
    float* __restrict__ vol) {
  const int bid = blockIdx.x, tid = threadIdx.x;
  if (bid >= 32) {
    int g = (bid - 32) * 256 + tid;  // 0..75775
    float v;
    if (g < 2048) {
      int h = g >> 5, k = g & 31;
      v = (k < 5) ? p1[k * 64 + h] : 0.f;
    } else if (g < 4096) {
      int loc = g - 2048, h = loc >> 5, k = loc & 31;
      v = (k < 30) ? p2[k * 64 + h] : 0.f;
    } else if (g < 14336) {
      int loc = g - 4096, h = loc / 160, k = loc - h * 160;
      v = (k < 155) ? p3[k * 64 + h] : 0.f;
    } else if (g < 24576) {
      int loc = g - 14336, h = loc / 160, k = loc - h * 160;
      v = (k < 155) ? p4[k * 64 + h] : 0.f;
    } else {
      int loc = g - 24576, row = loc >> 5, j = loc & 31;
      int i = row >> 6, h = row & 63;
      v = (j < 25) ? p4[(155 + i * 25 + j) * 64 + h] : 0.f;
    }
    unsigned short hi, lo;
    splitTrunc(v, hi, lo);
    WtH[g] = hi;
    WtL[g] = lo;
    return;
  }
  // ---- scan row bid ----
  __shared__ float sAbs[TT];
  __shared__ float sPart[256];
  const float* fb = F + (size_t)bid * TT * 5;
#pragma unroll
  for (int u = 0; u < 8; ++u) {
    int t = u * 256 + tid;
    float rv = (t > 0) ? (fb[t * 5] - fb[(t - 1) * 5]) : 0.f;
    ret[bid * TT + t] = rv;
    sAbs[t] = fabsf(rv);
  }
  __syncthreads();
  float loc8[8], run = 0.f;
#pragma unroll
  for (int u = 0; u < 8; ++u) {
    run += sAbs[tid * 8 + u];
    loc8[u] = run;
  }
  sPart[tid] = run;
  __syncthreads();
  for (int off = 1; off < 256; off <<= 1) {
    float v = (tid >= off) ? sPart[tid - off] : 0.f;
    __syncthreads();
    sPart[tid] += v;
    __syncthreads();
  }
  float excl = sPart[tid] - run;
#pragma unroll
  for (int u = 0; u < 8; ++u) {
    int t = tid * 8 + u;
    vol[bid * TT + t] = (excl + loc8[u]) / ((float)(t + 1) + 1e-8f);
  }
}

// ============== Kernel 2: gate MLP + signature + MFMA projections + head ==============
// (512,4): 128-VGPR cap. (512,6)=85-cap caused a spill cliff (r5: 678 MB
// scratch). r6 still spilled ~300 MB: the 160-thread signature phase kept
// ~55 live floats vs the allocator's 64. Fix: 800 thin tasks (p,e,f),
// ~25 live floats each — spill-free by construction.
__global__ __launch_bounds__(512, 4) void sig_kernel(
    const float* __restrict__ F, const float* __restrict__ ret_g,
    const float* __restrict__ vol_g, const unsigned short* __restrict__ WtH,
    const unsigned short* __restrict__ WtL, const float* __restrict__ hw1,
    const float* __restrict__ hb1, const float* __restrict__ hw2,
    const float* __restrict__ hb2, const float* __restrict__ hw3,
    const float* __restrict__ hb3, const float* __restrict__ gw1,
    const float* __restrict__ gb1, const float* __restrict__ gw2,
    const float* __restrict__ gb2, const float* __restrict__ p1b,
    const float* __restrict__ p2b, const float* __restrict__ p3b,
    const float* __restrict__ p4b, const float* __restrict__ w1,
    const float* __restrict__ b1, const float* __restrict__ gam,
    const float* __restrict__ bet, const float* __restrict__ rmean,
    const float* __restrict__ rvar, const float* __restrict__ w2,
    const float* __restrict__ b2, const float* __restrict__ w3,
    const float* __restrict__ b3, float* __restrict__ out) {
  // phi: k in [0,160): lvl1[0,5) l2[5,30) l3[30,155) zero[155,160). stride 168
  __shared__ unsigned short phiH[32][168];
  __shared__ unsigned short phiL[32][168];
  __shared__ unsigned short l2bH[32][40];  // l2 as K=32 B-operand (zero [25,32))
  __shared__ unsigned short l2bL[32][40];
  __shared__ float sL2[32 * 25];           // fp32 l2 for the l4 fold scale
  __shared__ __align__(16) float sF[44 * 8];  // F rows t0-10..t0+31, ch-pad 8
  __shared__ float retl[42];
  __shared__ float voll[32];
  __shared__ float sGate[32 * 4];
  // sU: gate sH1[32*33=1056] | epilogue sSig[32*68=2176] + sBn@2176[32*68]
  __shared__ __align__(16) float sU[4352];

  const int tid = threadIdx.x;
  const int b = blockIdx.x >> 6;
  const int t0 = (blockIdx.x & 63) << 5;
  const float* fb = F + (size_t)b * TT * 5;

  // ---- stage F window + ret window + vol + static zero-pads ----
  for (int u = tid; u < 668; u += 512) {
    if (u < 210) {
      int j = u / 5, ch = u - 5 * j;
      int t = t0 - 10 + j;
      sF[j * 8 + ch] = (t >= 0) ? fb[t * 5 + ch] : 0.f;
    } else if (u < 252) {
      int jj = u - 210;
      int t = t0 - 10 + jj;
      retl[jj] = (t >= 0) ? ret_g[b * TT + t] : 0.f;
    } else if (u < 284) {
      int p = u - 252;
      voll[p] = vol_g[b * TT + t0 + p];
    } else if (u < 444) {
      int v = u - 284;
      int p = v / 5, k = 155 + (v - 5 * (v / 5));
      phiH[p][k] = 0;
      phiL[p][k] = 0;
    } else {
      int v = u - 444;
      int p = v / 7, k = 25 + (v - 7 * (v / 7));
      l2bH[p][k] = 0;
      l2bL[p][k] = 0;
    }
  }
  __syncthreads();

  // ---- gate MLP: 16 threads per position, shuffle-reduced ----
  {
    float* sH1 = sU;  // [32][33]
    const int p = tid >> 4, q = tid & 15;
    const int t = t0 + p;
    const int soff = (t >= W) ? p : (W - t0);
    float r0[W];
#pragma unroll
    for (int u = 0; u < W; ++u) r0[u] = retl[soff + u];
    const int j = q * 2;
    float ax = hb1[j], ay = hb1[j + 1];
#pragma unroll
    for (int u = 0; u < W; ++u) {
      float2 w = *(const float2*)&hw1[u * 32 + j];
      ax = fmaf(r0[u], w.x, ax);
      ay = fmaf(r0[u], w.y, ay);
    }
    sH1[p * 33 + j] = fmaxf(ax, 0.f);
    sH1[p * 33 + j + 1] = fmaxf(ay, 0.f);
    // same-wave producer/consumer (p-group = 16 contiguous lanes) — no barrier
    float bx = hb2[j], by = hb2[j + 1];
    for (int u2 = 0; u2 < 32; ++u2) {
      float hv = sH1[p * 33 + u2];
      float2 w = *(const float2*)&hw2[u2 * 32 + j];
      bx = fmaf(hv, w.x, bx);
      by = fmaf(hv, w.y, by);
    }
    float hsp = fmaxf(bx, 0.f) * hw3[j] + fmaxf(by, 0.f) * hw3[j + 1];
    hsp += __shfl_xor(hsp, 1);
    hsp += __shfl_xor(hsp, 2);
    hsp += __shfl_xor(hsp, 4);
    hsp += __shfl_xor(hsp, 8);
    float H = 0.5f / (1.f + expf(-(hsp + hb3[0])));
    float vv = voll[p];
    float l0 = 0.f, l1 = 0.f, l2v = 0.f, l3v = 0.f;
#pragma unroll
    for (int d = 0; d < 2; ++d) {
      int j3 = q * 2 + d;
      float z = fmaxf(fmaf(H, gw1[j3], fmaf(vv, gw1[32 + j3], gb1[j3])), 0.f);
      l0 = fmaf(z, gw2[j3 * 4 + 0], l0);
      l1 = fmaf(z, gw2[j3 * 4 + 1], l1);
      l2v = fmaf(z, gw2[j3 * 4 + 2], l2v);
      l3v = fmaf(z, gw2[j3 * 4 + 3], l3v);
    }
#pragma unroll
    for (int m = 1; m <= 8; m <<= 1) {
      l0 += __shfl_xor(l0, m);
      l1 += __shfl_xor(l1, m);
      l2v += __shfl_xor(l2v, m);
      l3v += __shfl_xor(l3v, m);
    }
    if (q == 0) {
      l0 += gb2[0]; l1 += gb2[1]; l2v += gb2[2]; l3v += gb2[3];
      float mx = fmaxf(fmaxf(l0, l1), fmaxf(l2v, l3v));
      float e0 = expf(l0 - mx), e1 = expf(l1 - mx);
      float e2 = expf(l2v - mx), e3 = expf(l3v - mx);
      float inv = 1.f / (e0 + e1 + e2 + e3);
      *(float4*)&sGate[p * 4] = make_float4(e0 * inv, e1 * inv, e2 * inv, e3 * inv);
    }
  }
  // no barrier: signature phase touches disjoint LDS; barrier below covers all.

  // ---- signature: 800 thin tasks = 32 pos x 25 (e,f); ~25 live regs ----
#pragma unroll
  for (int pass = 0; pass < 2; ++pass) {
    const int task = pass * 512 + tid;
    if (task < 800) {
      const int p = task / 25, ef = task - 25 * (task / 25);
      const int e = ef / 5, f = ef - 5 * (ef / 5);
      float cur[5], d[5];
      float l3a[5] = {0.f, 0.f, 0.f, 0.f, 0.f};
      float a = 0.f, svf = 0.f;
#pragma unroll
      for (int i = 0; i < 5; ++i) cur[i] = sF[(p + 10) * 8 + i];
      for (int r = 9; r >= 0; --r) {
        const float m = ((t0 != 0) || (p + r >= 10)) ? 1.f : 0.f;
#pragma unroll
        for (int i = 0; i < 5; ++i) {
          float nx = sF[(p + r) * 8 + i];
          d[i] = (cur[i] - nx) * m;
          cur[i] = nx;
        }
        svf += sel5(d, f);  // S[r][f] inclusive suffix
#pragma unroll
        for (int i = 0; i < 5; ++i) l3a[i] = fmaf(d[i], a, l3a[i]);  // strict RA
        a = fmaf(sel5(d, e), svf, a);
      }
      unsigned short hi, lo;
      splitTrunc(a, hi, lo);
      phiH[p][5 + ef] = hi;
      phiL[p][5 + ef] = lo;
      l2bH[p][ef] = hi;
      l2bL[p][ef] = lo;
      sL2[p * 25 + ef] = a;
#pragma unroll
      for (int i = 0; i < 5; ++i) {
        splitTrunc(l3a[i], hi, lo);
        phiH[p][30 + i * 25 + ef] = hi;
        phiL[p][30 + i * 25 + ef] = lo;
      }
      if (e == 0) {  // lvl1[f] = S[0][f]
        splitTrunc(svf, hi, lo);
        phiH[p][f] = hi;
        phiL[p][f] = lo;
      }
    }
  }
  __syncthreads();

  // ---- MFMA projections: wave = (pos-tile, h-tile) ----
  {
    const int lane = tid & 63, wv = tid >> 6;
    const int ptile = wv & 1, htile = wv >> 1;
    const int col = lane & 15, quad = lane >> 4;
    const int pl = ptile * 16 + col;
    const int arow = htile * 16 + col;
    const f32x4 z4 = {0.f, 0.f, 0.f, 0.f};
    f32x4 acc1 = z4, acc2 = z4, acc3a = z4, acc3b = z4;
    f32x4 acc4a = z4, acc4b = z4, acc4c = z4;

    const unsigned short* W4aH = WtH + 14336 + arow * 160 + quad * 8;
    const unsigned short* W4aL = WtL + 14336 + arow * 160 + quad * 8;
    const unsigned short* W3H_ = WtH + 4096 + arow * 160 + quad * 8;
    const unsigned short* W3L_ = WtL + 4096 + arow * 160 + quad * 8;
#pragma unroll
    for (int s = 0; s < 5; ++s) {
      bf16x8 bh = *(const bf16x8*)&phiH[pl][s * 32 + quad * 8];
      bf16x8 bl = *(const bf16x8*)&phiL[pl][s * 32 + quad * 8];
      bf16x8 ah = *(const bf16x8*)(W4aH + s * 32);
      bf16x8 al = *(const bf16x8*)(W4aL + s * 32);
      acc4a = MFMA16(ah, bh, acc4a);
      acc4b = MFMA16(ah, bl, acc4b);
      acc4b = MFMA16(al, bh, acc4b);
      bf16x8 ch = *(const bf16x8*)(W3H_ + s * 32);
      bf16x8 cl = *(const bf16x8*)(W3L_ + s * 32);
      acc3a = MFMA16(ch, bh, acc3a);
      acc3b = MFMA16(ch, bl, acc3b);
      acc3b = MFMA16(cl, bh, acc3b);
      if (s == 0) {
        bf16x8 dh = *(const bf16x8*)(WtH + 2048 + arow * 32 + quad * 8);
        bf16x8 dl = *(const bf16x8*)(WtL + 2048 + arow * 32 + quad * 8);
        acc2 = MFMA16(dh, bh, acc2);
        acc2 = MFMA16(dh, bl, acc2);
        acc2 = MFMA16(dl, bh, acc2);
        bf16x8 eh = *(const bf16x8*)(WtH + arow * 32 + quad * 8);
        bf16x8 el = *(const bf16x8*)(WtL + arow * 32 + quad * 8);
        acc1 = MFMA16(eh, bh, acc1);
        acc1 = MFMA16(eh, bl, acc1);
        acc1 = MFMA16(el, bh, acc1);
      }
    }
    // l4 factorized: per i, K=32 GEMM on l2 B-frag + fp32 fold by l2[i,pos]
    bf16x8 b2h = *(const bf16x8*)&l2bH[pl][quad * 8];
    bf16x8 b2l = *(const bf16x8*)&l2bL[pl][quad * 8];
    const unsigned short* W4bH = WtH + 24576 + arow * 32 + quad * 8;
    const unsigned short* W4bL = WtL + 24576 + arow * 32 + quad * 8;
    const float* l2row = sL2 + pl * 25;
    for (int i = 0; i < 25; ++i) {
      bf16x8 ah = *(const bf16x8*)(W4bH + i * 2048);
      bf16x8 al = *(const bf16x8*)(W4bL + i * 2048);
      f32x4 t4 = MFMA16(ah, b2h, z4);
      t4 = MFMA16(ah, b2l, t4);
      t4 = MFMA16(al, b2h, t4);
      float scl = l2row[i];
      acc4c[0] = fmaf(scl, t4[0], acc4c[0]);
      acc4c[1] = fmaf(scl, t4[1], acc4c[1]);
      acc4c[2] = fmaf(scl, t4[2], acc4c[2]);
      acc4c[3] = fmaf(scl, t4[3], acc4c[3]);
    }
    // gate combine -> sSig (C/D layout: col->pos, quad*4+r->h)
    const int t = t0 + pl;
    float g0 = sGate[pl * 4 + 0];
    float g1 = (t >= 1) ? sGate[pl * 4 + 1] : 0.f;
    float g2 = (t >= 2) ? sGate[pl * 4 + 2] : 0.f;
    float g3 = (t >= 3) ? sGate[pl * 4 + 3] : 0.f;
    float* sSig = sU;  // [32][68]
#pragma unroll
    for (int r = 0; r < 4; ++r) {
      int h = htile * 16 + quad * 4 + r;
      float v = g0 * (acc1[r] + p1b[h]) + g1 * (acc2[r] + p2b[h]) +
                g2 * (acc3a[r] + acc3b[r] + p3b[h]) +
                g3 * (acc4a[r] + acc4b[r] + acc4c[r] + p4b[h]);
      sSig[pl * 68 + h] = v;
    }
  }
  __syncthreads();

  // ---- head h1 + BN: wave -> 4 positions, lane = channel j ----
  {
    const float* sSig = sU;
    float* sBn = sU + 2176;  // [32][68]
    const int lane = tid & 63, wv = tid >> 6;
    const int j = lane;
    const int p0 = wv * 4;
    float a0 = b1[j], a1 = a0, a2 = a0, a3 = a0;
    for (int i = 0; i < 64; i += 4) {
      float4 s0 = *(const float4*)&sSig[(p0 + 0) * 68 + i];
      float4 s1 = *(const float4*)&sSig[(p0 + 1) * 68 + i];
      float4 s2 = *(const float4*)&sSig[(p0 + 2) * 68 + i];
      float4 s3 = *(const float4*)&sSig[(p0 + 3) * 68 + i];
      float wa = w1[(i + 0) * 64 + j];
      float wb = w1[(i + 1) * 64 + j];
      float wc = w1[(i + 2) * 64 + j];
      float wd = w1[(i + 3) * 64 + j];
      a0 = fmaf(s0.x, wa, a0); a0 = fmaf(s0.y, wb, a0);
      a0 = fmaf(s0.z, wc, a0); a0 = fmaf(s0.w, wd, a0);
      a1 = fmaf(s1.x, wa, a1); a1 = fmaf(s1.y, wb, a1);
      a1 = fmaf(s1.z, wc, a1); a1 = fmaf(s1.w, wd, a1);
      a2 = fmaf(s2.x, wa, a2); a2 = fmaf(s2.y, wb, a2);
      a2 = fmaf(s2.z, wc, a2); a2 = fmaf(s2.w, wd, a2);
      a3 = fmaf(s3.x, wa, a3); a3 = fmaf(s3.y, wb, a3);
      a3 = fmaf(s3.z, wc, a3); a3 = fmaf(s3.w, wd, a3);
    }
#pragma unroll
    for (int i = 0; i < 5; ++i) {
      float wt = w1[(64 + i) * 64 + j];
      a0 = fmaf(sF[(p0 + 10) * 8 + i], wt, a0);
      a1 = fmaf(sF[(p0 + 11) * 8 + i], wt, a1);
      a2 = fmaf(sF[(p0 + 12) * 8 + i], wt, a2);
      a3 = fmaf(sF[(p0 + 13) * 8 + i], wt, a3);
    }
    float sc = gam[j] * rsqrtf(rvar[j] + 1e-5f);
    float rm = rmean[j], be = bet[j];
    sBn[(p0 + 0) * 68 + j] = fmaf(fmaxf(a0, 0.f) - rm, sc, be);
    sBn[(p0 + 1) * 68 + j] = fmaf(fmaxf(a1, 0.f) - rm, sc, be);
    sBn[(p0 + 2) * 68 + j] = fmaf(fmaxf(a2, 0.f) - rm, sc, be);
    sBn[(p0 + 3) * 68 + j] = fmaf(fmaxf(a3, 0.f) - rm, sc, be);
  }
  __syncthreads();

  // ---- h2 + output: 1024 tasks = 32 pos x 32 k, 2 passes ----
  {
    const float* sBn = sU + 2176;
    const float b3s = b3[0];
#pragma unroll
    for (int pass = 0; pass < 2; ++pass) {
      int task = tid + pass * 512;
      int p = task >> 5, k = task & 31;
      const float* bnp = sBn + p * 68;
      float a = b2[k];
      for (int jj = 0; jj < 64; jj += 4) {
        float4 bn4 = *(const float4*)&bnp[jj];
        a = fmaf(bn4.x, w2[(jj + 0) * 32 + k], a);
        a = fmaf(bn4.y, w2[(jj + 1) * 32 + k], a);
        a = fmaf(bn4.z, w2[(jj + 2) * 32 + k], a);
        a = fmaf(bn4.w, w2[(jj + 3) * 32 + k], a);
      }
      float partial = fmaxf(a, 0.f) * w3[k];
#pragma unroll
      for (int off = 16; off >= 1; off >>= 1)
        partial += __shfl_xor(partial, off, 32);
      if (k == 0) out[b * TT + t0 + p] = 1.5f * tanhf(partial + b3s);
    }
  }
}

extern "C" void kernel_launch(void* const* d_in, const int* in_sizes, int n_in,
                              void* d_out, int out_size, void* d_ws, size_t ws_size,
                              hipStream_t stream) {
  const float* F = (const float*)d_in[0];
  const float* hw1 = (const float*)d_in[1];
  const float* hb1 = (const float*)d_in[2];
  const float* hw2 = (const float*)d_in[3];
  const float* hb2 = (const float*)d_in[4];
  const float* hw3 = (const float*)d_in[5];
  const float* hb3 = (const float*)d_in[6];
  const float* gw1 = (const float*)d_in[7];
  const float* gb1 = (const float*)d_in[8];
  const float* gw2 = (const float*)d_in[9];
  const float* gb2 = (const float*)d_in[10];
  const float* p1 = (const float*)d_in[11];
  const float* p1b = (const float*)d_in[12];
  const float* p2 = (const float*)d_in[13];
  const float* p2b = (const float*)d_in[14];
  const float* p3 = (const float*)d_in[15];
  const float* p3b = (const float*)d_in[16];
  const float* p4 = (const float*)d_in[17];
  const float* p4b = (const float*)d_in[18];
  const float* w1 = (const float*)d_in[19];
  const float* b1 = (const float*)d_in[20];
  const float* gam = (const float*)d_in[21];
  const float* bet = (const float*)d_in[22];
  const float* rmean = (const float*)d_in[23];
  const float* rvar = (const float*)d_in[24];
  const float* w2 = (const float*)d_in[25];
  const float* b2 = (const float*)d_in[26];
  const float* w3 = (const float*)d_in[27];
  const float* b3 = (const float*)d_in[28];

  float* ws = (float*)d_ws;
  float* ret = ws;                                       // 65536 floats
  float* vol = ws + 65536;                               // 65536 floats
  unsigned short* WtH = (unsigned short*)(ws + 131072);  // 75776 ushorts
  unsigned short* WtL = WtH + 75776;                     // 75776 ushorts
  float* out = (float*)d_out;                            // 65536 floats

  prep_kernel<<<328, 256, 0, stream>>>(F, p1, p2, p3, p4, WtH, WtL, ret, vol);
  sig_kernel<<<2048, 512, 0, stream>>>(F, ret, vol, WtH, WtL, hw1, hb1, hw2,
                                       hb2, hw3, hb3, gw1, gb1, gw2, gb2, p1b,
                                       p2b, p3b, p4b, w1, b1, gam, bet, rmean,
                                       rvar, w2, b2, w3, b3, out);
}

// Round 8
// 274.208 us; speedup vs baseline: 1.1632x; 1.1632x over previous
//
#include <hip/hip_runtime.h>
#include <math.h>

#define TT 2048
#define W 10

typedef short bf16x8 __attribute__((ext_vector_type(8)));
typedef float f32x4 __attribute__((ext_vector_type(4)));

#define MFMA16(a, b, c) __builtin_amdgcn_mfma_f32_16x16x32_bf16((a), (b), (c), 0, 0, 0)

// Truncation hi/lo bf16 split: lo absorbs hi's truncation error; residual ~2^-16.
__device__ __forceinline__ void splitTrunc(float v, unsigned short& hi,
                                           unsigned short& lo) {
  unsigned int u = __float_as_uint(v);
  hi = (unsigned short)(u >> 16);
  float r = v - __uint_as_float(u & 0xffff0000u);
  lo = (unsigned short)(__float_as_uint(r) >> 16);
}

// ============== Kernel 1: row scan (ret, vol) + weight repack ==============
__global__ __launch_bounds__(256) void prep_kernel(
    const float* __restrict__ F, const float* __restrict__ p1,
    const float* __restrict__ p2, const float* __restrict__ p3,
    const float* __restrict__ p4, unsigned short* __restrict__ WtH,
    unsigned short* __restrict__ WtL, float* __restrict__ ret,
    float* __restrict__ vol) {
  const int bid = blockIdx.x, tid = threadIdx.x;
  if (bid >= 32) {
    int g = (bid - 32) * 256 + tid;  // 0..75775
    float v;
    if (g < 2048) {
      int h = g >> 5, k = g & 31;
      v = (k < 5) ? p1[k * 64 + h] : 0.f;
    } else if (g < 4096) {
      int loc = g - 2048, h = loc >> 5, k = loc & 31;
      v = (k < 30) ? p2[k * 64 + h] : 0.f;
    } else if (g < 14336) {
      int loc = g - 4096, h = loc / 160, k = loc - h * 160;
      v = (k < 155) ? p3[k * 64 + h] : 0.f;
    } else if (g < 24576) {
      int loc = g - 14336, h = loc / 160, k = loc - h * 160;
      v = (k < 155) ? p4[k * 64 + h] : 0.f;
    } else {
      int loc = g - 24576, row = loc >> 5, j = loc & 31;
      int i = row >> 6, h = row & 63;
      v = (j < 25) ? p4[(155 + i * 25 + j) * 64 + h] : 0.f;
    }
    unsigned short hi, lo;
    splitTrunc(v, hi, lo);
    WtH[g] = hi;
    WtL[g] = lo;
    return;
  }
  // ---- scan row bid ----
  __shared__ float sAbs[TT];
  __shared__ float sPart[256];
  const float* fb = F + (size_t)bid * TT * 5;
#pragma unroll
  for (int u = 0; u < 8; ++u) {
    int t = u * 256 + tid;
    float rv = (t > 0) ? (fb[t * 5] - fb[(t - 1) * 5]) : 0.f;
    ret[bid * TT + t] = rv;
    sAbs[t] = fabsf(rv);
  }
  __syncthreads();
  float loc8[8], run = 0.f;
#pragma unroll
  for (int u = 0; u < 8; ++u) {
    run += sAbs[tid * 8 + u];
    loc8[u] = run;
  }
  sPart[tid] = run;
  __syncthreads();
  for (int off = 1; off < 256; off <<= 1) {
    float v = (tid >= off) ? sPart[tid - off] : 0.f;
    __syncthreads();
    sPart[tid] += v;
    __syncthreads();
  }
  float excl = sPart[tid] - run;
#pragma unroll
  for (int u = 0; u < 8; ++u) {
    int t = tid * 8 + u;
    vol[bid * TT + t] = (excl + loc8[u]) / ((float)(t + 1) + 1e-8f);
  }
}

// ============== Kernel 2: gate MLP + signature + MFMA projections + head ==============
// EMPIRICAL (r5/r6/r7 VGPR evidence): on this compiler the 2nd launch_bounds
// arg for 512-thread blocks acts as WORKGROUPS/CU: cap = 2048/(arg*8 waves).
// (512,4) -> 64-reg cap (r6: spilled ~300MB), (512,6) -> 40 (r5: 678MB).
// (512,2) -> 128-reg cap: fits the ~90-reg live set, 2 blocks/CU.
__global__ __launch_bounds__(512, 2) void sig_kernel(
    const float* __restrict__ F, const float* __restrict__ ret_g,
    const float* __restrict__ vol_g, const unsigned short* __restrict__ WtH,
    const unsigned short* __restrict__ WtL, const float* __restrict__ hw1,
    const float* __restrict__ hb1, const float* __restrict__ hw2,
    const float* __restrict__ hb2, const float* __restrict__ hw3,
    const float* __restrict__ hb3, const float* __restrict__ gw1,
    const float* __restrict__ gb1, const float* __restrict__ gw2,
    const float* __restrict__ gb2, const float* __restrict__ p1b,
    const float* __restrict__ p2b, const float* __restrict__ p3b,
    const float* __restrict__ p4b, const float* __restrict__ w1,
    const float* __restrict__ b1, const float* __restrict__ gam,
    const float* __restrict__ bet, const float* __restrict__ rmean,
    const float* __restrict__ rvar, const float* __restrict__ w2,
    const float* __restrict__ b2, const float* __restrict__ w3,
    const float* __restrict__ b3, float* __restrict__ out) {
  // phi: k in [0,160): lvl1[0,5) l2[5,30) l3[30,155) zero[155,160). stride 168
  __shared__ unsigned short phiH[32][168];
  __shared__ unsigned short phiL[32][168];
  __shared__ unsigned short l2bH[32][40];  // l2 as K=32 B-operand (zero [25,32))
  __shared__ unsigned short l2bL[32][40];
  __shared__ float sL2[32 * 25];           // fp32 l2 for the l4 fold scale
  __shared__ __align__(16) float sF[44 * 8];  // F rows t0-10..t0+31, ch-pad 8
  __shared__ float retl[42];
  __shared__ float voll[32];
  __shared__ float sGate[32 * 4];
  // sU: gate sH1[32*33=1056] | epilogue sSig[32*68=2176] + sBn@2176[32*68]
  __shared__ __align__(16) float sU[4352];

  const int tid = threadIdx.x;
  const int b = blockIdx.x >> 6;
  const int t0 = (blockIdx.x & 63) << 5;
  const float* fb = F + (size_t)b * TT * 5;

  // ---- stage F window + ret window + vol ----
  for (int u = tid; u < 284; u += 512) {
    if (u < 210) {
      int j = u / 5, ch = u - 5 * j;
      int t = t0 - 10 + j;
      sF[j * 8 + ch] = (t >= 0) ? fb[t * 5 + ch] : 0.f;
    } else if (u < 252) {
      int jj = u - 210;
      int t = t0 - 10 + jj;
      retl[jj] = (t >= 0) ? ret_g[b * TT + t] : 0.f;
    } else {
      int p = u - 252;
      voll[p] = vol_g[b * TT + t0 + p];
    }
  }
  __syncthreads();

  // ---- gate MLP: 16 threads per position, shuffle-reduced ----
  {
    float* sH1 = sU;  // [32][33]
    const int p = tid >> 4, q = tid & 15;
    const int t = t0 + p;
    const int soff = (t >= W) ? p : (W - t0);
    float r0[W];
#pragma unroll
    for (int u = 0; u < W; ++u) r0[u] = retl[soff + u];
    const int j = q * 2;
    float ax = hb1[j], ay = hb1[j + 1];
#pragma unroll
    for (int u = 0; u < W; ++u) {
      float2 w = *(const float2*)&hw1[u * 32 + j];
      ax = fmaf(r0[u], w.x, ax);
      ay = fmaf(r0[u], w.y, ay);
    }
    sH1[p * 33 + j] = fmaxf(ax, 0.f);
    sH1[p * 33 + j + 1] = fmaxf(ay, 0.f);
    // same-wave producer/consumer (p-group = 16 contiguous lanes) — no barrier
    float bx = hb2[j], by = hb2[j + 1];
    for (int u2 = 0; u2 < 32; ++u2) {
      float hv = sH1[p * 33 + u2];
      float2 w = *(const float2*)&hw2[u2 * 32 + j];
      bx = fmaf(hv, w.x, bx);
      by = fmaf(hv, w.y, by);
    }
    float hsp = fmaxf(bx, 0.f) * hw3[j] + fmaxf(by, 0.f) * hw3[j + 1];
    hsp += __shfl_xor(hsp, 1);
    hsp += __shfl_xor(hsp, 2);
    hsp += __shfl_xor(hsp, 4);
    hsp += __shfl_xor(hsp, 8);
    float H = 0.5f / (1.f + expf(-(hsp + hb3[0])));
    float vv = voll[p];
    float l0 = 0.f, l1 = 0.f, l2v = 0.f, l3v = 0.f;
#pragma unroll
    for (int d = 0; d < 2; ++d) {
      int j3 = q * 2 + d;
      float z = fmaxf(fmaf(H, gw1[j3], fmaf(vv, gw1[32 + j3], gb1[j3])), 0.f);
      l0 = fmaf(z, gw2[j3 * 4 + 0], l0);
      l1 = fmaf(z, gw2[j3 * 4 + 1], l1);
      l2v = fmaf(z, gw2[j3 * 4 + 2], l2v);
      l3v = fmaf(z, gw2[j3 * 4 + 3], l3v);
    }
#pragma unroll
    for (int m = 1; m <= 8; m <<= 1) {
      l0 += __shfl_xor(l0, m);
      l1 += __shfl_xor(l1, m);
      l2v += __shfl_xor(l2v, m);
      l3v += __shfl_xor(l3v, m);
    }
    if (q == 0) {
      l0 += gb2[0]; l1 += gb2[1]; l2v += gb2[2]; l3v += gb2[3];
      float mx = fmaxf(fmaxf(l0, l1), fmaxf(l2v, l3v));
      float e0 = expf(l0 - mx), e1 = expf(l1 - mx);
      float e2 = expf(l2v - mx), e3 = expf(l3v - mx);
      float inv = 1.f / (e0 + e1 + e2 + e3);
      *(float4*)&sGate[p * 4] = make_float4(e0 * inv, e1 * inv, e2 * inv, e3 * inv);
    }
  }
  // no barrier: next phase touches disjoint LDS; barrier below covers sGate/sH1.

  // ---- signature levels 1-3 in registers: thread = (p, e), 160 threads ----
  if (tid < 160) {
    const int p = tid / 5, e = tid - 5 * (tid / 5);
    float aA[5] = {0.f, 0.f, 0.f, 0.f, 0.f};
    float sv[5] = {0.f, 0.f, 0.f, 0.f, 0.f};
    float l3m[5][5];
#pragma unroll
    for (int i = 0; i < 5; ++i)
#pragma unroll
      for (int fi = 0; fi < 5; ++fi) l3m[i][fi] = 0.f;
    float4 c4 = *(const float4*)&sF[(p + 10) * 8];
    float ce = sF[(p + 10) * 8 + 4];
    float cur[5] = {c4.x, c4.y, c4.z, c4.w, ce};
#pragma unroll
    for (int r = 9; r >= 0; --r) {
      float4 n4 = *(const float4*)&sF[(p + r) * 8];
      float ne = sF[(p + r) * 8 + 4];
      float nxt[5] = {n4.x, n4.y, n4.z, n4.w, ne};
      float m = ((t0 != 0) || (p + r >= 10)) ? 1.f : 0.f;
      float d[5];
#pragma unroll
      for (int i = 0; i < 5; ++i) d[i] = (cur[i] - nxt[i]) * m;
#pragma unroll
      for (int fi = 0; fi < 5; ++fi) sv[fi] += d[fi];  // S[r] inclusive suffix
#pragma unroll
      for (int i = 0; i < 5; ++i)
#pragma unroll
        for (int fi = 0; fi < 5; ++fi) l3m[i][fi] = fmaf(d[i], aA[fi], l3m[i][fi]);
      float de = (e == 0) ? d[0] : (e == 1) ? d[1] : (e == 2) ? d[2]
                : (e == 3) ? d[3] : d[4];
#pragma unroll
      for (int fi = 0; fi < 5; ++fi) aA[fi] = fmaf(de, sv[fi], aA[fi]);
#pragma unroll
      for (int i = 0; i < 5; ++i) cur[i] = nxt[i];
    }
    unsigned short hi, lo;
#pragma unroll
    for (int fi = 0; fi < 5; ++fi) {
      float a = aA[fi];
      int ef = e * 5 + fi;
      sL2[p * 25 + ef] = a;
      splitTrunc(a, hi, lo);
      phiH[p][5 + ef] = hi;
      phiL[p][5 + ef] = lo;
      l2bH[p][ef] = hi;
      l2bL[p][ef] = lo;
#pragma unroll
      for (int i = 0; i < 5; ++i) {
        splitTrunc(l3m[i][fi], hi, lo);
        phiH[p][30 + i * 25 + ef] = hi;
        phiL[p][30 + i * 25 + ef] = lo;
      }
    }
    if (e == 0) {
#pragma unroll
      for (int i = 0; i < 5; ++i) {
        splitTrunc(sv[i], hi, lo);
        phiH[p][i] = hi;
        phiL[p][i] = lo;
      }
    }
  } else {
    // zero pads (NaN safety): phi[155,160) (160 tasks) + l2b[25,32) (224 tasks)
    for (int u = tid - 160; u < 384; u += 352) {
      if (u < 160) {
        int p = u / 5, k = 155 + (u - 5 * (u / 5));
        phiH[p][k] = 0;
        phiL[p][k] = 0;
      } else {
        int v = u - 160;
        int p = v / 7, k = 25 + (v - 7 * (v / 7));
        l2bH[p][k] = 0;
        l2bL[p][k] = 0;
      }
    }
  }
  __syncthreads();

  // ---- MFMA projections: wave = (pos-tile, h-tile) ----
  {
    const int lane = tid & 63, wv = tid >> 6;
    const int ptile = wv & 1, htile = wv >> 1;
    const int col = lane & 15, quad = lane >> 4;
    const int pl = ptile * 16 + col;
    const int arow = htile * 16 + col;
    const f32x4 z4 = {0.f, 0.f, 0.f, 0.f};
    f32x4 acc1 = z4, acc2 = z4, acc3a = z4, acc3b = z4;
    f32x4 acc4a = z4, acc4b = z4, acc4c = z4;

    const unsigned short* W4aH = WtH + 14336 + arow * 160 + quad * 8;
    const unsigned short* W4aL = WtL + 14336 + arow * 160 + quad * 8;
    const unsigned short* W3H_ = WtH + 4096 + arow * 160 + quad * 8;
    const unsigned short* W3L_ = WtL + 4096 + arow * 160 + quad * 8;
#pragma unroll
    for (int s = 0; s < 5; ++s) {
      bf16x8 bh = *(const bf16x8*)&phiH[pl][s * 32 + quad * 8];
      bf16x8 bl = *(const bf16x8*)&phiL[pl][s * 32 + quad * 8];
      bf16x8 ah = *(const bf16x8*)(W4aH + s * 32);
      bf16x8 al = *(const bf16x8*)(W4aL + s * 32);
      acc4a = MFMA16(ah, bh, acc4a);
      acc4b = MFMA16(ah, bl, acc4b);
      acc4b = MFMA16(al, bh, acc4b);
      bf16x8 ch = *(const bf16x8*)(W3H_ + s * 32);
      bf16x8 cl = *(const bf16x8*)(W3L_ + s * 32);
      acc3a = MFMA16(ch, bh, acc3a);
      acc3b = MFMA16(ch, bl, acc3b);
      acc3b = MFMA16(cl, bh, acc3b);
      if (s == 0) {
        bf16x8 dh = *(const bf16x8*)(WtH + 2048 + arow * 32 + quad * 8);
        bf16x8 dl = *(const bf16x8*)(WtL + 2048 + arow * 32 + quad * 8);
        acc2 = MFMA16(dh, bh, acc2);
        acc2 = MFMA16(dh, bl, acc2);
        acc2 = MFMA16(dl, bh, acc2);
        bf16x8 eh = *(const bf16x8*)(WtH + arow * 32 + quad * 8);
        bf16x8 el = *(const bf16x8*)(WtL + arow * 32 + quad * 8);
        acc1 = MFMA16(eh, bh, acc1);
        acc1 = MFMA16(eh, bl, acc1);
        acc1 = MFMA16(el, bh, acc1);
      }
    }
    // l4 factorized: per i, K=32 GEMM on l2 B-frag + fp32 fold by l2[i,pos]
    bf16x8 b2h = *(const bf16x8*)&l2bH[pl][quad * 8];
    bf16x8 b2l = *(const bf16x8*)&l2bL[pl][quad * 8];
    const unsigned short* W4bH = WtH + 24576 + arow * 32 + quad * 8;
    const unsigned short* W4bL = WtL + 24576 + arow * 32 + quad * 8;
    const float* l2row = sL2 + pl * 25;
    for (int i = 0; i < 25; ++i) {
      bf16x8 ah = *(const bf16x8*)(W4bH + i * 2048);
      bf16x8 al = *(const bf16x8*)(W4bL + i * 2048);
      f32x4 t4 = MFMA16(ah, b2h, z4);
      t4 = MFMA16(ah, b2l, t4);
      t4 = MFMA16(al, b2h, t4);
      float scl = l2row[i];
      acc4c[0] = fmaf(scl, t4[0], acc4c[0]);
      acc4c[1] = fmaf(scl, t4[1], acc4c[1]);
      acc4c[2] = fmaf(scl, t4[2], acc4c[2]);
      acc4c[3] = fmaf(scl, t4[3], acc4c[3]);
    }
    // gate combine -> sSig (C/D layout: col->pos, quad*4+r->h)
    const int t = t0 + pl;
    float g0 = sGate[pl * 4 + 0];
    float g1 = (t >= 1) ? sGate[pl * 4 + 1] : 0.f;
    float g2 = (t >= 2) ? sGate[pl * 4 + 2] : 0.f;
    float g3 = (t >= 3) ? sGate[pl * 4 + 3] : 0.f;
    float* sSig = sU;  // [32][68]
#pragma unroll
    for (int r = 0; r < 4; ++r) {
      int h = htile * 16 + quad * 4 + r;
      float v = g0 * (acc1[r] + p1b[h]) + g1 * (acc2[r] + p2b[h]) +
                g2 * (acc3a[r] + acc3b[r] + p3b[h]) +
                g3 * (acc4a[r] + acc4b[r] + acc4c[r] + p4b[h]);
      sSig[pl * 68 + h] = v;
    }
  }
  __syncthreads();

  // ---- head h1 + BN: wave -> 4 positions, lane = channel j ----
  {
    const float* sSig = sU;
    float* sBn = sU + 2176;  // [32][68]
    const int lane = tid & 63, wv = tid >> 6;
    const int j = lane;
    const int p0 = wv * 4;
    float a0 = b1[j], a1 = a0, a2 = a0, a3 = a0;
    for (int i = 0; i < 64; i += 4) {
      float4 s0 = *(const float4*)&sSig[(p0 + 0) * 68 + i];
      float4 s1 = *(const float4*)&sSig[(p0 + 1) * 68 + i];
      float4 s2 = *(const float4*)&sSig[(p0 + 2) * 68 + i];
      float4 s3 = *(const float4*)&sSig[(p0 + 3) * 68 + i];
      float wa = w1[(i + 0) * 64 + j];
      float wb = w1[(i + 1) * 64 + j];
      float wc = w1[(i + 2) * 64 + j];
      float wd = w1[(i + 3) * 64 + j];
      a0 = fmaf(s0.x, wa, a0); a0 = fmaf(s0.y, wb, a0);
      a0 = fmaf(s0.z, wc, a0); a0 = fmaf(s0.w, wd, a0);
      a1 = fmaf(s1.x, wa, a1); a1 = fmaf(s1.y, wb, a1);
      a1 = fmaf(s1.z, wc, a1); a1 = fmaf(s1.w, wd, a1);
      a2 = fmaf(s2.x, wa, a2); a2 = fmaf(s2.y, wb, a2);
      a2 = fmaf(s2.z, wc, a2); a2 = fmaf(s2.w, wd, a2);
      a3 = fmaf(s3.x, wa, a3); a3 = fmaf(s3.y, wb, a3);
      a3 = fmaf(s3.z, wc, a3); a3 = fmaf(s3.w, wd, a3);
    }
#pragma unroll
    for (int i = 0; i < 5; ++i) {
      float wt = w1[(64 + i) * 64 + j];
      a0 = fmaf(sF[(p0 + 10) * 8 + i], wt, a0);
      a1 = fmaf(sF[(p0 + 11) * 8 + i], wt, a1);
      a2 = fmaf(sF[(p0 + 12) * 8 + i], wt, a2);
      a3 = fmaf(sF[(p0 + 13) * 8 + i], wt, a3);
    }
    float sc = gam[j] * rsqrtf(rvar[j] + 1e-5f);
    float rm = rmean[j], be = bet[j];
    sBn[(p0 + 0) * 68 + j] = fmaf(fmaxf(a0, 0.f) - rm, sc, be);
    sBn[(p0 + 1) * 68 + j] = fmaf(fmaxf(a1, 0.f) - rm, sc, be);
    sBn[(p0 + 2) * 68 + j] = fmaf(fmaxf(a2, 0.f) - rm, sc, be);
    sBn[(p0 + 3) * 68 + j] = fmaf(fmaxf(a3, 0.f) - rm, sc, be);
  }
  __syncthreads();

  // ---- h2 + output: 1024 tasks = 32 pos x 32 k, 2 passes ----
  {
    const float* sBn = sU + 2176;
    const float b3s = b3[0];
#pragma unroll
    for (int pass = 0; pass < 2; ++pass) {
      int task = tid + pass * 512;
      int p = task >> 5, k = task & 31;
      const float* bnp = sBn + p * 68;
      float a = b2[k];
      for (int jj = 0; jj < 64; jj += 4) {
        float4 bn4 = *(const float4*)&bnp[jj];
        a = fmaf(bn4.x, w2[(jj + 0) * 32 + k], a);
        a = fmaf(bn4.y, w2[(jj + 1) * 32 + k], a);
        a = fmaf(bn4.z, w2[(jj + 2) * 32 + k], a);
        a = fmaf(bn4.w, w2[(jj + 3) * 32 + k], a);
      }
      float partial = fmaxf(a, 0.f) * w3[k];
#pragma unroll
      for (int off = 16; off >= 1; off >>= 1)
        partial += __shfl_xor(partial, off, 32);
      if (k == 0) out[b * TT + t0 + p] = 1.5f * tanhf(partial + b3s);
    }
  }
}

extern "C" void kernel_launch(void* const* d_in, const int* in_sizes, int n_in,
                              void* d_out, int out_size, void* d_ws, size_t ws_size,
                              hipStream_t stream) {
  const float* F = (const float*)d_in[0];
  const float* hw1 = (const float*)d_in[1];
  const float* hb1 = (const float*)d_in[2];
  const float* hw2 = (const float*)d_in[3];
  const float* hb2 = (const float*)d_in[4];
  const float* hw3 = (const float*)d_in[5];
  const float* hb3 = (const float*)d_in[6];
  const float* gw1 = (const float*)d_in[7];
  const float* gb1 = (const float*)d_in[8];
  const float* gw2 = (const float*)d_in[9];
  const float* gb2 = (const float*)d_in[10];
  const float* p1 = (const float*)d_in[11];
  const float* p1b = (const float*)d_in[12];
  const float* p2 = (const float*)d_in[13];
  const float* p2b = (const float*)d_in[14];
  const float* p3 = (const float*)d_in[15];
  const float* p3b = (const float*)d_in[16];
  const float* p4 = (const float*)d_in[17];
  const float* p4b = (const float*)d_in[18];
  const float* w1 = (const float*)d_in[19];
  const float* b1 = (const float*)d_in[20];
  const float* gam = (const float*)d_in[21];
  const float* bet = (const float*)d_in[22];
  const float* rmean = (const float*)d_in[23];
  const float* rvar = (const float*)d_in[24];
  const float* w2 = (const float*)d_in[25];
  const float* b2 = (const float*)d_in[26];
  const float* w3 = (const float*)d_in[27];
  const float* b3 = (const float*)d_in[28];

  float* ws = (float*)d_ws;
  float* ret = ws;                                       // 65536 floats
  float* vol = ws + 65536;                               // 65536 floats
  unsigned short* WtH = (unsigned short*)(ws + 131072);  // 75776 ushorts
  unsigned short* WtL = WtH + 75776;                     // 75776 ushorts
  float* out = (float*)d_out;                            // 65536 floats

  prep_kernel<<<328, 256, 0, stream>>>(F, p1, p2, p3, p4, WtH, WtL, ret, vol);
  sig_kernel<<<2048, 512, 0, stream>>>(F, ret, vol, WtH, WtL, hw1, hb1, hw2,
                                       hb2, hw3, hb3, gw1, gb1, gw2, gb2, p1b,
                                       p2b, p3b, p4b, w1, b1, gam, bet, rmean,
                                       rvar, w2, b2, w3, b3, out);
}